// Round 2
// baseline (52.160 us; speedup 1.0000x reference)
//
#include <hip/hip_runtime.h>
#include <math.h>

// PathDDPM q_sample, fully fused single kernel.
// x_t = sqrt(acp[t[b]]) * x_0 + sqrt(1-acp[t[b]]) * noise ; out = [x_t | noise]
// B=4096, L=2048, C=2 -> 16,777,216 fp32 per tensor, 4,194,304 float4.

#define TSTEPS 1000
#define BSTART 1e-4
#define BEND   0.02

typedef float f4 __attribute__((ext_vector_type(4)));

__global__ void __launch_bounds__(256) ddpm_fused_kernel(
    const f4*  __restrict__ x0,
    const int* __restrict__ t,
    const f4*  __restrict__ nz,
    f4*        __restrict__ out_xt,
    f4*        __restrict__ out_nz)
{
    __shared__ float s_a[TSTEPS];  // sqrt(alphas_cumprod)
    __shared__ float s_s[TSTEPS];  // sqrt(1 - alphas_cumprod)

    // ---- wave 0: build schedule in LDS (fp64 chunked product + shuffle scan)
    if (threadIdx.x < 64) {
        const int lane = threadIdx.x;
        const double step = (BEND - BSTART) / (double)(TSTEPS - 1);
        const int i0 = lane * 16;                 // 64*16 = 1024 >= 1000

        double p = 1.0;
        #pragma unroll
        for (int k = 0; k < 16; ++k) {
            int i = i0 + k;
            if (i < TSTEPS) p *= (1.0 - (BSTART + step * (double)i));
        }
        double scan = p;
        #pragma unroll
        for (int off = 1; off < 64; off <<= 1) {
            double o = __shfl_up(scan, off);
            if (lane >= off) scan *= o;
        }
        double excl = __shfl_up(scan, 1);
        if (lane == 0) excl = 1.0;

        double run = excl;
        #pragma unroll
        for (int k = 0; k < 16; ++k) {
            int i = i0 + k;
            if (i < TSTEPS) {
                run *= (1.0 - (BSTART + step * (double)i));
                s_a[i] = (float)sqrt(run);
                s_s[i] = (float)sqrt(1.0 - run);
            }
        }
    }
    __syncthreads();

    // ---- main streaming loop: exactly 8 iterations per thread
    // grid = 2048 x 256 = 524288 threads; n4 = 4194304 = 8 * 524288.
    const int base = blockIdx.x * 256 + threadIdx.x;
    #pragma unroll
    for (int k = 0; k < 8; ++k) {
        const int i = base + k * 524288;
        // b = i >> 10 is uniform across the block (256 lanes span 1/4 of a
        // 1024-float4 row, never crossing a row boundary) -> scalar load.
        const int b  = __builtin_amdgcn_readfirstlane(i >> 10);
        const int tb = t[b];
        const float a = s_a[tb];
        const float s = s_s[tb];

        const f4 x = x0[i];
        const f4 n = nz[i];
        f4 o;
        o.x = fmaf(a, x.x, s * n.x);
        o.y = fmaf(a, x.y, s * n.y);
        o.z = fmaf(a, x.z, s * n.z);
        o.w = fmaf(a, x.w, s * n.w);
        // nontemporal: outputs are never re-read in-kernel; keep the L3 free
        // for the (L3-resident across replays) 134 MB of inputs.
        __builtin_nontemporal_store(o, &out_xt[i]);
        __builtin_nontemporal_store(n, &out_nz[i]);
    }
}

extern "C" void kernel_launch(void* const* d_in, const int* in_sizes, int n_in,
                              void* d_out, int out_size, void* d_ws, size_t ws_size,
                              hipStream_t stream) {
    const float* x0 = (const float*)d_in[0];   // [B, L, 2] fp32
    const int*   t  = (const int*)  d_in[1];   // [B] int32
    const float* nz = (const float*)d_in[2];   // [B, L, 2] fp32
    float* out = (float*)d_out;                // [x_t | noise] concatenated
    const int n = 4096 * 2048 * 2;             // elements per tensor

    ddpm_fused_kernel<<<2048, 256, 0, stream>>>(
        (const f4*)x0, t, (const f4*)nz,
        (f4*)out, (f4*)(out + n));
}

// Round 3
// 48.976 us; speedup vs baseline: 1.0650x; 1.0650x over previous
//
#include <hip/hip_runtime.h>

// PathDDPM q_sample, single pure-streaming kernel.
// x_t = sqrt(acp[t[b]]) * x_0 + sqrt(1-acp[t[b]]) * noise ; out = [x_t | noise]
// B=4096, L=2048, C=2 -> 16,777,216 fp32 per tensor, 4,194,304 float4.
// The schedule (sqrt(alphas_cumprod), sqrt(1-alphas_cumprod)) is a
// compile-time constant -> baked into __constant__ via constexpr eval.

#define TSTEPS 1000

typedef float f4 __attribute__((ext_vector_type(4)));

// Compile-time sqrt: Newton iteration in double, x in (0, 2). 32 iterations
// from g=1 converges to full double precision for x down to ~1e-10.
constexpr double csqrt(double x) {
    double g = 1.0;
    for (int i = 0; i < 32; ++i) g = 0.5 * (g + x / g);
    return g;
}

struct Tables { float a[TSTEPS]; float s[TSTEPS]; };

constexpr Tables make_tables() {
    Tables tb{};
    const double step = (0.02 - 1e-4) / (double)(TSTEPS - 1);
    double run = 1.0;
    for (int i = 0; i < TSTEPS; ++i) {
        run *= (1.0 - (1e-4 + step * (double)i));
        tb.a[i] = (float)csqrt(run);
        tb.s[i] = (float)csqrt(1.0 - run);
    }
    return tb;
}

__constant__ Tables c_tab = make_tables();

__global__ void __launch_bounds__(256) ddpm_stream_kernel(
    const f4*  __restrict__ x0,
    const int* __restrict__ t,
    const f4*  __restrict__ nz,
    f4*        __restrict__ out_xt,
    f4*        __restrict__ out_nz)
{
    // grid = 2048 x 256 = 524288 threads; n4 = 4194304 = 8 * 524288.
    const int base = blockIdx.x * 256 + threadIdx.x;

    // Hoist all 8 (a,s) scalar pairs up front. b = i >> 10 is block-uniform
    // (256 lanes span 1/4 of a 1024-float4 row) -> pure SGPR chain, no LDS.
    float a[8], s[8];
    #pragma unroll
    for (int k = 0; k < 8; ++k) {
        const int i  = base + k * 524288;
        const int b  = __builtin_amdgcn_readfirstlane(i >> 10);
        const int tb = __builtin_amdgcn_readfirstlane(t[b]);
        a[k] = c_tab.a[tb];
        s[k] = c_tab.s[tb];
    }

    // Pure streaming: 8 x {2 loads, 4 fma, 2 nontemporal stores}.
    #pragma unroll
    for (int k = 0; k < 8; ++k) {
        const int i = base + k * 524288;
        const f4 x = x0[i];
        const f4 n = nz[i];
        f4 o;
        o.x = fmaf(a[k], x.x, s[k] * n.x);
        o.y = fmaf(a[k], x.y, s[k] * n.y);
        o.z = fmaf(a[k], x.z, s[k] * n.z);
        o.w = fmaf(a[k], x.w, s[k] * n.w);
        // Outputs are never re-read: nontemporal keeps L3 free for the
        // (replay-resident) 134 MB of inputs.
        __builtin_nontemporal_store(o, &out_xt[i]);
        __builtin_nontemporal_store(n, &out_nz[i]);
    }
}

extern "C" void kernel_launch(void* const* d_in, const int* in_sizes, int n_in,
                              void* d_out, int out_size, void* d_ws, size_t ws_size,
                              hipStream_t stream) {
    const float* x0 = (const float*)d_in[0];   // [B, L, 2] fp32
    const int*   t  = (const int*)  d_in[1];   // [B] int32
    const float* nz = (const float*)d_in[2];   // [B, L, 2] fp32
    float* out = (float*)d_out;                // [x_t | noise] concatenated
    const int n = 4096 * 2048 * 2;             // elements per tensor

    ddpm_stream_kernel<<<2048, 256, 0, stream>>>(
        (const f4*)x0, t, (const f4*)nz,
        (f4*)out, (f4*)(out + n));
}

// Round 4
// 43.777 us; speedup vs baseline: 1.1915x; 1.1188x over previous
//
#include <hip/hip_runtime.h>

// PathDDPM q_sample, single streaming kernel, load-batched for MLP.
// x_t = sqrt(acp[t[b]]) * x_0 + sqrt(1-acp[t[b]]) * noise ; out = [x_t | noise]
// B=4096, L=2048, C=2 -> 16,777,216 fp32 per tensor, 4,194,304 float4.
// Schedule tables baked into __constant__ at compile time.

#define TSTEPS 1000

typedef float f4 __attribute__((ext_vector_type(4)));

constexpr double csqrt(double x) {
    double g = 1.0;
    for (int i = 0; i < 32; ++i) g = 0.5 * (g + x / g);
    return g;
}

struct Tables { float a[TSTEPS]; float s[TSTEPS]; };

constexpr Tables make_tables() {
    Tables tb{};
    const double step = (0.02 - 1e-4) / (double)(TSTEPS - 1);
    double run = 1.0;
    for (int i = 0; i < TSTEPS; ++i) {
        run *= (1.0 - (1e-4 + step * (double)i));
        tb.a[i] = (float)csqrt(run);
        tb.s[i] = (float)csqrt(1.0 - run);
    }
    return tb;
}

__constant__ Tables c_tab = make_tables();

// Each block owns a contiguous 2048-float4 (128 KB) span = exactly 2 rows
// (row = 1024 float4). grid 2048 x 256 covers all 4,194,304 float4.
__global__ void __launch_bounds__(256) ddpm_stream_kernel(
    const f4*  __restrict__ x0,
    const int* __restrict__ t,
    const f4*  __restrict__ nz,
    f4*        __restrict__ out_xt,
    f4*        __restrict__ out_nz)
{
    const int base = blockIdx.x * 2048 + threadIdx.x;

    // Two rows per block -> two scalar (a,s) pairs, pure SGPR path.
    const int t0 = t[2 * blockIdx.x];
    const int t1 = t[2 * blockIdx.x + 1];
    const float a0 = c_tab.a[t0], sc0 = c_tab.s[t0];
    const float a1 = c_tab.a[t1], sc1 = c_tab.s[t1];

    // Phase 1: issue ALL 16 loads back-to-back (16 KB in flight per wave).
    f4 x[8], n[8];
    #pragma unroll
    for (int k = 0; k < 8; ++k) x[k] = x0[base + k * 256];
    #pragma unroll
    for (int k = 0; k < 8; ++k) n[k] = nz[base + k * 256];

    // Phase 2: fma + nontemporal stores (outputs never re-read; keep L3
    // free for the replay-resident inputs).
    #pragma unroll
    for (int k = 0; k < 8; ++k) {
        const float a = (k < 4) ? a0 : a1;
        const float s = (k < 4) ? sc0 : sc1;
        f4 o;
        o.x = fmaf(a, x[k].x, s * n[k].x);
        o.y = fmaf(a, x[k].y, s * n[k].y);
        o.z = fmaf(a, x[k].z, s * n[k].z);
        o.w = fmaf(a, x[k].w, s * n[k].w);
        __builtin_nontemporal_store(o,    &out_xt[base + k * 256]);
        __builtin_nontemporal_store(n[k], &out_nz[base + k * 256]);
    }
}

extern "C" void kernel_launch(void* const* d_in, const int* in_sizes, int n_in,
                              void* d_out, int out_size, void* d_ws, size_t ws_size,
                              hipStream_t stream) {
    const float* x0 = (const float*)d_in[0];   // [B, L, 2] fp32
    const int*   t  = (const int*)  d_in[1];   // [B] int32
    const float* nz = (const float*)d_in[2];   // [B, L, 2] fp32
    float* out = (float*)d_out;                // [x_t | noise] concatenated
    const int n = 4096 * 2048 * 2;             // elements per tensor

    ddpm_stream_kernel<<<2048, 256, 0, stream>>>(
        (const f4*)x0, t, (const f4*)nz,
        (f4*)out, (f4*)(out + n));
}